// Round 2
// baseline (369.146 us; speedup 1.0000x reference)
//
#include <hip/hip_runtime.h>
#include <math.h>

// Problem: N=100000 nodes, D=512, E=6400000 edges.
// gate[n] = sigmoid(dot(x[n,:], p) + b)
// out[0:2E)   = float(edge_index)            (tuple output 0, exact in f32)
// out[2E:3E)  = edge_attr[e] * gate[col[e]]  (col = edge_index[E + e])
//
// Traffic floor: read x 204.8 MB + edge_index 51.2 MB + edge_attr 25.6 MB,
// write 76.8 MB + gate 0.4 MB = 358.8 MB -> ~57 us at 6.3 TB/s.

// ---------------- Kernel 1: per-row matvec + sigmoid -----------------
// One wave (64 lanes) per row. D=512 = 64 lanes * 8 floats -> each lane
// reads 32 contiguous bytes; the wave covers the full 2 KB row coalesced.
// p (2 KB) is loaded once per wave and stays L1-resident.
__global__ __launch_bounds__(256) void gate_kernel(
    const float* __restrict__ x,
    const float* __restrict__ p,
    const float* __restrict__ b,
    float* __restrict__ gate,
    int N)
{
    const int wave_id = (blockIdx.x * blockDim.x + threadIdx.x) >> 6;
    const int lane    = threadIdx.x & 63;
    const float bb = b[0];

    const float4* pr = (const float4*)p;
    float4 p0 = pr[lane * 2];
    float4 p1 = pr[lane * 2 + 1];

    if (wave_id >= N) return;
    const float4* xr = (const float4*)(x + (size_t)wave_id * 512);
    float4 x0 = xr[lane * 2];
    float4 x1 = xr[lane * 2 + 1];
    float s = x0.x * p0.x + x0.y * p0.y + x0.z * p0.z + x0.w * p0.w
            + x1.x * p1.x + x1.y * p1.y + x1.z * p1.z + x1.w * p1.w;
    // wave64 butterfly reduction
    #pragma unroll
    for (int off = 32; off > 0; off >>= 1)
        s += __shfl_down(s, off, 64);
    if (lane == 0) {
        float t = s + bb;
        gate[wave_id] = 1.0f / (1.0f + __expf(-t));
    }
}

// ------- Kernel 2: fused index convert + edge gather/scale -------
// One thread per value-quad. Each thread:
//   reads  row0 quad (16 B), col quad (16 B), attr quad (16 B)  -- all coalesced
//   writes float(row0) quad, float(col) quad, value quad (48 B) -- all coalesced
//   + 4 scalar gathers from the 400 KB gate table (L2-resident per XCD).
// Col half of edge_index is read exactly once (was read twice before).
__global__ __launch_bounds__(256) void edge_kernel(
    const int*   __restrict__ edge_index,  // [2*E] int32
    const float* __restrict__ edge_attr,   // [E]
    const float* __restrict__ gate,        // [N]
    float* __restrict__ out,               // [3*E] f32
    int E)
{
    const int i   = blockIdx.x * blockDim.x + threadIdx.x;
    const int EV4 = E >> 2;                // quads per row of edge_index
    if (i >= EV4) return;

    const int4* row4 = (const int4*)edge_index;
    const int4* col4 = (const int4*)(edge_index + E);
    int4 rq = row4[i];
    int4 cq = col4[i];
    float4 aq = ((const float4*)edge_attr)[i];

    // gathers issued early so latency overlaps the converts/stores
    float g0 = gate[cq.x];
    float g1 = gate[cq.y];
    float g2 = gate[cq.z];
    float g3 = gate[cq.w];

    float4* out4 = (float4*)out;
    out4[i]       = make_float4((float)rq.x, (float)rq.y, (float)rq.z, (float)rq.w);
    out4[EV4 + i] = make_float4((float)cq.x, (float)cq.y, (float)cq.z, (float)cq.w);

    float4 r;
    r.x = aq.x * g0;
    r.y = aq.y * g1;
    r.z = aq.z * g2;
    r.w = aq.w * g3;
    ((float4*)(out + 2 * (size_t)E))[i] = r;
}

extern "C" void kernel_launch(void* const* d_in, const int* in_sizes, int n_in,
                              void* d_out, int out_size, void* d_ws, size_t ws_size,
                              hipStream_t stream) {
    const float* x          = (const float*)d_in[0];   // [N, 512]
    const int*   edge_index = (const int*)  d_in[1];   // [2, E] int32 on device
    const float* edge_attr  = (const float*)d_in[2];   // [E]
    const float* p          = (const float*)d_in[3];   // [512, 1]
    const float* b          = (const float*)d_in[4];   // [1]

    const int D = in_sizes[3];            // 512
    const int N = in_sizes[0] / D;        // 100000
    const int E = in_sizes[2];            // 6400000

    float* gate = (float*)d_ws;           // N floats = 400 KB scratch
    float* out  = (float*)d_out;

    // Kernel 1: one wave per row -> N waves -> N/4 blocks of 256
    int gate_blocks = (N + 3) / 4;        // 25000
    gate_kernel<<<gate_blocks, 256, 0, stream>>>(x, p, b, gate, N);

    // Kernel 2: one thread per value-quad -> E/4 threads
    int edge_blocks = ((E >> 2) + 255) / 256;   // 6250
    edge_kernel<<<edge_blocks, 256, 0, stream>>>(edge_index, edge_attr, gate, out, E);
}